// Round 9
// baseline (117.402 us; speedup 1.0000x reference)
//
#include <hip/hip_runtime.h>
#include <math.h>

// GEBLNet via Gram-matrix reduction.
// R26 = R25 + HALF-MACRO chain split: every complex-MAC macro was 2
// serially-dependent v_pk_fma_f32 (both into %0). The two halves are
// algebraically independent -> feed SEPARATE accumulators:
//   inst A: acc += (cc.x*ee.x, cc.x*ee.y)   [src0 = cc.lo broadcast]
//   inst B: acc += (-cc.y*ee.y, cc.y*ee.x)  [src0 = cc.hi broadcast]
// Chains double again with zero extra loads/FMAs (one add per output):
//   2a: 8 chains (even/odd-w x A/B, depth ~6.5 -> issue-bound),
//   2b: 6 chains, P4: 4 chains, P5: 8 chains (named accs, rule #20).
// EVIDENCE: R24 (issue cut, -4.3us) + R25 (chain split, -3us) both hit;
// latency-bound at ~3 waves/SIMD confirmed; no pipe >40% busy.
// LEDGER: falsified = VMEM count (R21), DS count (R23), residency
// (R17-R20), pt amortization (R22). Proven = conflict removal (R18),
// load-ILP (R19), pk-fma packing (R24), chain split (R25).
// LESSON (R23): avoid pad-14 layouts. LESSON (R22): 2 pts/wave regress.
// LESSON (R20): multi-wave wgs regress. LESSON (R16): full 2a+2b merge
// regress. LESSON (R4+R7): launch_bounds min-waves arg -> spill.
// LESSON (R6): unions, no reinterpret-cast of locals.

#define NPTS 8192
#define THRESH 0.001f

typedef float f32x2 __attribute__((ext_vector_type(2)));

// --- independent halves of complex MAC: acc += cc * ee ---
// A: acc += (cc.x*ee.x, cc.x*ee.y)
static __device__ __forceinline__ void cmacA(f32x2& acc, f32x2 cc, f32x2 ee) {
    asm("v_pk_fma_f32 %0, %1, %2, %0 op_sel:[0,0,0] op_sel_hi:[0,1,1]"
        : "+v"(acc) : "v"(cc), "v"(ee));
}
// B: acc += (-cc.y*ee.y, cc.y*ee.x)
static __device__ __forceinline__ void cmacB(f32x2& acc, f32x2 cc, f32x2 ee) {
    asm("v_pk_fma_f32 %0, %1, %2, %0 op_sel:[1,1,0] op_sel_hi:[1,0,1] neg_lo:[1,0,0]"
        : "+v"(acc) : "v"(cc), "v"(ee));
}
// --- independent halves of conj MAC: acc += A * conj(B) ---
// A: acc += (A.x*B.x, -A.x*B.y)
static __device__ __forceinline__ void cmaccA(f32x2& acc, f32x2 A, f32x2 B) {
    asm("v_pk_fma_f32 %0, %1, %2, %0 op_sel:[0,0,0] op_sel_hi:[0,1,1] neg_hi:[1,0,0]"
        : "+v"(acc) : "v"(A), "v"(B));
}
// B: acc += (A.y*B.y, A.y*B.x)
static __device__ __forceinline__ void cmaccB(f32x2& acc, f32x2 A, f32x2 B) {
    asm("v_pk_fma_f32 %0, %1, %2, %0 op_sel:[1,1,0] op_sel_hi:[1,0,1]"
        : "+v"(acc) : "v"(A), "v"(B));
}
// --- independent halves of P5 dot: acc += gv.lo*cA ; acc += gv.hi*cB ---
static __device__ __forceinline__ void cdotA(f32x2& acc, f32x2 gv, f32x2 cA) {
    asm("v_pk_fma_f32 %0, %1, %2, %0 op_sel:[0,0,0] op_sel_hi:[0,1,1]"
        : "+v"(acc) : "v"(gv), "v"(cA));
}
static __device__ __forceinline__ void cdotB(f32x2& acc, f32x2 gv, f32x2 cB) {
    asm("v_pk_fma_f32 %0, %1, %2, %0 op_sel:[1,0,0] op_sel_hi:[1,1,1]"
        : "+v"(acc) : "v"(gv), "v"(cB));
}

static __device__ __forceinline__ f32x2 c2(float2 a) {
    f32x2 r; r.x = a.x; r.y = a.y; return r;
}

__global__ void geblnet_setup(const float* __restrict__ w2,
                              float4* __restrict__ CTt) {
    int j = blockIdx.x * blockDim.x + threadIdx.x;
    if (j >= 12 * 169) return;
    int u = j / 169, it = j % 169;
    const float* W = w2 + u * 25 * 25 * 2;
#define WR(v, w) W[((v) * 25 + (w)) * 2]
#define WI(v, w) W[((v) * 25 + (w)) * 2 + 1]
    float c0, c1, c2v, c3;
    if (it < 78) {                       // S pairs, a<=b
        int q = it, a = 0;
        while (q >= 12 - a) { q -= 12 - a; ++a; }
        int b = a + q;
        float ar = WR(a, b) + (a != b ? WR(b, a) : 0.f);
        float ai = WI(a, b) + (a != b ? WI(b, a) : 0.f);
        float br = WR(12 + a, 12 + b) + (a != b ? WR(12 + b, 12 + a) : 0.f);
        float bi = WI(12 + a, 12 + b) + (a != b ? WI(12 + b, 12 + a) : 0.f);
        c0 = ar + br; c1 = bi - ai; c2v = ai + bi; c3 = ar - br;
    } else if (it < 156) {               // Hm pairs, a<=b
        int q = it - 78, a = 0;
        while (q >= 12 - a) { q -= 12 - a; ++a; }
        int b = a + q;
        if (a != b) {
            float gr = WR(a, 12 + b) + WR(12 + b, a);
            float gi = WI(a, 12 + b) + WI(12 + b, a);
            float dr = WR(b, 12 + a) + WR(12 + a, b);
            float di = WI(b, 12 + a) + WI(12 + a, b);
            c0 = gr + dr; c1 = di - gi; c2v = gi + di; c3 = gr - dr;
        } else {
            float er = WR(a, 12 + a) + WR(12 + a, a);
            float ei = WI(a, 12 + a) + WI(12 + a, a);
            c0 = er; c1 = 0.f; c2v = ei; c3 = 0.f;
        }
    } else if (it < 168) {               // trace terms
        int a = it - 156;
        float fr = WR(a, 24) + WR(24, a), fi = WI(a, 24) + WI(24, a);
        float pr = WR(12 + a, 24) + WR(24, 12 + a);
        float pi = WI(12 + a, 24) + WI(24, 12 + a);
        c0 = fr + pr; c1 = pi - fi; c2v = fi + pi; c3 = fr - pr;
    } else {                             // unit-unit
        c0 = 3.f * WR(24, 24); c1 = 0.f; c2v = 3.f * WI(24, 24); c3 = 0.f;
    }
    // Packed layout for P5: pairs (c0,c2) and (c1,c3) adjacent.
    CTt[it * 12 + u] = make_float4(c0, c2v, c1, c3);
#undef WR
#undef WI
}

// Scratch union: bs dead after phase 2b; phase-3..6 scratch reuses it.
union Scr {
    float2 bs[702];                     // B[uu][v][jk], rows exact 9 (5616 B)
    struct {
        float2 tpar[60];                // phase 5 partials
        float2 tr1[12];                 // layer-1 traces (read in phase 4)
        float  sc1[12];                 // combined gerelu+trnorm scale
    } s;
};

__global__ __launch_bounds__(64) void geblnet_main(
    const float2* __restrict__ x2,      // (8192, 10, 9) complex
    const float2* __restrict__ w1g,     // (12,13,13) complex
    const float* __restrict__ dw,       // (24,)
    const float* __restrict__ db,       // (1,)
    const float4* __restrict__ CTt,     // (169,12) packed (c0,c2,c1,c3)
    float* __restrict__ out)            // (8192,)
{
    // Overlay: phases 1-2 = We row-major (13 ch incl. identity, stride 10);
    //          phases 4-5 = GV[169].
    __shared__ float2 WeGV[170];        // 1360 B
    __shared__ Scr S;                   // 5616 B
    __shared__ float2 Hs[108];          //  864 B
    // total 7840 B -> 8192 alloc

    const int t = threadIdx.x;
    const int p = blockIdx.x;

    // ---- phase 1: ONE coalesced read of x channels 4..9 (54 float2),
    //      write both We layouts (direct ch 0..5, conj-T ch 6..11) + identity.
    if (t < 54) {
        int xc = t / 9, ik = t - xc * 9;
        int i = ik / 3, j = ik - i * 3;
        float2 val = x2[(size_t)p * 90 + 36 + t];       // contiguous 432 B
        WeGV[xc * 10 + ik] = val;                        // direct
        WeGV[(6 + xc) * 10 + j * 3 + i] = make_float2(val.x, -val.y); // conj-T
    } else if (t < 63) {
        int ik = t - 54;
        WeGV[120 + ik] = make_float2((ik % 4 == 0) ? 1.f : 0.f, 0.f); // identity
    }
    __syncthreads();

    // ---- phase 2: layer 1 on all 64 lanes, two u-half passes
    #pragma unroll 1
    for (int g = 0; g < 2; ++g) {
        const int u0 = g * 6;
        // 2a: B[uu][v][jk] = sum_w w1[u0+uu,v,w] * We[w][jk]
        //     8 chains: even/odd-w x A/B half-macros, depth ~6.5 each.
        {
            int uu = 0, rem = t;
            #pragma unroll 2
            for (int e = t; e < 702; e += 64) {
                int v = rem / 9, jk = rem - v * 9;
                const float2* cp = w1g + ((u0 + uu) * 13 + v) * 13; // contiguous
                f32x2 a0A = {0.f, 0.f}, a0B = {0.f, 0.f};
                f32x2 a1A = {0.f, 0.f}, a1B = {0.f, 0.f};
                #pragma unroll
                for (int w = 0; w < 12; w += 2) {
                    f32x2 c0 = c2(cp[w]),     e0 = c2(WeGV[w * 10 + jk]);
                    f32x2 c1 = c2(cp[w + 1]), e1 = c2(WeGV[(w + 1) * 10 + jk]);
                    cmacA(a0A, c0, e0);
                    cmacB(a0B, c0, e0);
                    cmacA(a1A, c1, e1);
                    cmacB(a1B, c1, e1);
                }
                {
                    f32x2 c0 = c2(cp[12]), e0 = c2(WeGV[120 + jk]);
                    cmacA(a0A, c0, e0);
                    cmacB(a0B, c0, e0);
                }
                S.bs[(uu * 13 + v) * 9 + jk] =
                    make_float2((a0A.x + a0B.x) + (a1A.x + a1B.x),
                                (a0A.y + a0B.y) + (a1A.y + a1B.y));
                rem += 64;
                if (rem >= 117) { rem -= 117; ++uu; }
            }
        }
        __syncthreads();
        // 2b: H[u0+uu][i][k] = sum_{v,j} We[v][i][j] * B[uu][v][j*3+k]
        //     6 chains: 3 j-accs x A/B.
        if (t < 54) {
            int uu = t / 9, ik = t - uu * 9;
            int i = ik / 3, k = ik - i * 3;
            f32x2 h0A = {0.f, 0.f}, h0B = {0.f, 0.f};
            f32x2 h1A = {0.f, 0.f}, h1B = {0.f, 0.f};
            f32x2 h2A = {0.f, 0.f}, h2B = {0.f, 0.f};
            #pragma unroll
            for (int v = 0; v < 13; ++v) {
                const float2* a = &WeGV[v * 10 + i * 3];
                const float2* b = &S.bs[(uu * 13 + v) * 9 + k];
                f32x2 a0 = c2(a[0]), b0 = c2(b[0]);
                f32x2 a1 = c2(a[1]), b1 = c2(b[3]);
                f32x2 a2 = c2(a[2]), b2 = c2(b[6]);
                cmacA(h0A, a0, b0); cmacB(h0B, a0, b0);
                cmacA(h1A, a1, b1); cmacB(h1B, a1, b1);
                cmacA(h2A, a2, b2); cmacB(h2B, a2, b2);
            }
            Hs[(u0 + uu) * 9 + ik] =
                make_float2((h0A.x + h0B.x) + (h1A.x + h1B.x) + (h2A.x + h2B.x),
                            (h0A.y + h0B.y) + (h1A.y + h1B.y) + (h2A.y + h2B.y));
        }
        __syncthreads();
    }

    // ---- phase 3: traces + gerelu + trnorm scales (shuffle reduce, 1 barrier)
    {
        float2 tt = make_float2(0.f, 0.f);
        float gg = 0.f, tra_v = 0.f;
        if (t < 12) {
            float2 a = Hs[t * 9 + 0], b = Hs[t * 9 + 4], c = Hs[t * 9 + 8];
            tt = make_float2(a.x + b.x + c.x, a.y + b.y + c.y);
            gg = tt.x > 0.f ? tt.x : 0.f;
            tra_v = gg * sqrtf(tt.x * tt.x + tt.y * tt.y);
        }
        float m = tra_v;                 // lanes 12..15 contribute 0
        m += __shfl_xor(m, 1, 16);
        m += __shfl_xor(m, 2, 16);
        m += __shfl_xor(m, 4, 16);
        m += __shfl_xor(m, 8, 16);
        if (t < 12) {
            S.s.tr1[t] = tt;
            S.s.sc1[t] = gg / fmaxf(m * (1.f / 12.f), THRESH);
        }
    }
    __syncthreads();

    // ---- phase 4: Gram values -> GV (overlays We row-major; dead now)
    //      4 chains: element parity x A/B.
    for (int it = t; it < 169; it += 64) {
        float2 val;
        if (it < 156) {
            int q = it < 78 ? it : it - 78;
            float fs = sqrtf(625.0f - 8.0f * (float)q);   // exact at bucket edges
            int a = (int)((25.0f - fs) * 0.5f);
            int b = q - (a * (25 - a)) / 2 + a;
            const float2* Ha = &Hs[a * 9];
            const float2* Hb = &Hs[b * 9];
            float s = S.s.sc1[a] * S.s.sc1[b];
            f32x2 v0A = {0.f, 0.f}, v0B = {0.f, 0.f};
            f32x2 v1A = {0.f, 0.f}, v1B = {0.f, 0.f};
            if (it < 78) {                    // S = tr(Aa Ab)
                #pragma unroll
                for (int i = 0; i < 3; ++i)
                    #pragma unroll
                    for (int jj = 0; jj < 3; ++jj) {
                        f32x2 A = c2(Ha[i * 3 + jj]), B = c2(Hb[jj * 3 + i]);
                        if (((i * 3 + jj) & 1) == 0) {
                            cmacA(v0A, A, B); cmacB(v0B, A, B);
                        } else {
                            cmacA(v1A, A, B); cmacB(v1B, A, B);
                        }
                    }
            } else {                          // Hm = tr(Aa Ab^H)
                #pragma unroll
                for (int e = 0; e < 9; ++e) {
                    f32x2 A = c2(Ha[e]), B = c2(Hb[e]);
                    if ((e & 1) == 0) { cmaccA(v0A, A, B); cmaccB(v0B, A, B); }
                    else              { cmaccA(v1A, A, B); cmaccB(v1B, A, B); }
                }
            }
            val = make_float2(s * ((v0A.x + v0B.x) + (v1A.x + v1B.x)),
                              s * ((v0A.y + v0B.y) + (v1A.y + v1B.y)));
        } else if (it < 168) {
            int a = it - 156;
            float s = S.s.sc1[a]; float2 tt = S.s.tr1[a];
            val = make_float2(s * tt.x, s * tt.y);
        } else {
            val = make_float2(1.f, 0.f);
        }
        WeGV[it] = val;
    }
    __syncthreads();

    // ---- phase 5: coefficient contraction, lane=(q,u), 60 active
    //      8 chains: 4x unroll x A/B, all NAMED accumulators.
    if (t < 60) {
        int q = t / 12, u = t - q * 12;
        int i0 = q * 34, i1 = (q == 4) ? 169 : i0 + 34;
        f32x2 A0 = {0.f, 0.f}, B0 = {0.f, 0.f};
        f32x2 A1 = {0.f, 0.f}, B1 = {0.f, 0.f};
        f32x2 A2 = {0.f, 0.f}, B2 = {0.f, 0.f};
        f32x2 A3 = {0.f, 0.f}, B3 = {0.f, 0.f};
        int it = i0;
        #pragma unroll 1
        for (; it + 4 <= i1; it += 4) {
            float4 c0v = CTt[(it + 0) * 12 + u];
            float4 c1v = CTt[(it + 1) * 12 + u];
            float4 c2c = CTt[(it + 2) * 12 + u];
            float4 c3v = CTt[(it + 3) * 12 + u];
            f32x2 g0 = c2(WeGV[it + 0]), g1 = c2(WeGV[it + 1]);
            f32x2 g2 = c2(WeGV[it + 2]), g3 = c2(WeGV[it + 3]);
            f32x2 cA, cB;
            cA.x = c0v.x; cA.y = c0v.y; cB.x = c0v.z; cB.y = c0v.w;
            cdotA(A0, g0, cA); cdotB(B0, g0, cB);
            cA.x = c1v.x; cA.y = c1v.y; cB.x = c1v.z; cB.y = c1v.w;
            cdotA(A1, g1, cA); cdotB(B1, g1, cB);
            cA.x = c2c.x; cA.y = c2c.y; cB.x = c2c.z; cB.y = c2c.w;
            cdotA(A2, g2, cA); cdotB(B2, g2, cB);
            cA.x = c3v.x; cA.y = c3v.y; cB.x = c3v.z; cB.y = c3v.w;
            cdotA(A3, g3, cA); cdotB(B3, g3, cB);
        }
        for (; it < i1; ++it) {
            float4 c = CTt[it * 12 + u];
            f32x2 cA, cB;
            cA.x = c.x; cA.y = c.y; cB.x = c.z; cB.y = c.w;
            f32x2 g = c2(WeGV[it]);
            cdotA(A0, g, cA); cdotB(B0, g, cB);
        }
        S.s.tpar[u * 5 + q] =
            make_float2(((A0.x + B0.x) + (A1.x + B1.x)) +
                        ((A2.x + B2.x) + (A3.x + B3.x)),
                        ((A0.y + B0.y) + (A1.y + B1.y)) +
                        ((A2.y + B2.y) + (A3.y + B3.y)));
    }
    __syncthreads();

    // ---- phase 6: layer-2 gerelu + trnorm + dense head (shuffle, 0 barrier)
    {
        float2 tt = make_float2(0.f, 0.f);
        float gg = 0.f, tra_v = 0.f;
        if (t < 12) {
            #pragma unroll
            for (int q = 0; q < 5; ++q) {
                float2 A = S.s.tpar[t * 5 + q];
                tt.x += A.x; tt.y += A.y;
            }
            gg = tt.x > 0.f ? tt.x : 0.f;
            tra_v = gg * sqrtf(tt.x * tt.x + tt.y * tt.y);
        }
        float m = tra_v;                 // lanes 12..15 contribute 0
        m += __shfl_xor(m, 1, 16);
        m += __shfl_xor(m, 2, 16);
        m += __shfl_xor(m, 4, 16);
        m += __shfl_xor(m, 8, 16);
        float term = 0.f;
        if (t < 12) {
            float inv = 1.f / fmaxf(m * (1.f / 12.f), THRESH);
            float s = gg * inv * (1.f / 3.f);
            term = s * (tt.x * dw[2 * t] + tt.y * dw[2 * t + 1]);
        }
        term += __shfl_xor(term, 1, 16);
        term += __shfl_xor(term, 2, 16);
        term += __shfl_xor(term, 4, 16);
        term += __shfl_xor(term, 8, 16);
        if (t == 0) out[p] = term + db[0];
    }
}

extern "C" void kernel_launch(void* const* d_in, const int* in_sizes, int n_in,
                              void* d_out, int out_size, void* d_ws, size_t ws_size,
                              hipStream_t stream) {
    const float* x  = (const float*)d_in[0];
    const float* w1 = (const float*)d_in[1];
    const float* w2 = (const float*)d_in[2];
    const float* dw = (const float*)d_in[3];
    const float* db = (const float*)d_in[4];
    float* outp = (float*)d_out;
    float4* CTt = (float4*)d_ws;          // 12*169*16 B = 32448 B

    geblnet_setup<<<(12 * 169 + 255) / 256, 256, 0, stream>>>(w2, CTt);

    geblnet_main<<<NPTS, 64, 0, stream>>>(
        (const float2*)x, (const float2*)w1, dw, db, CTt, outp);
}

// Round 11
// 115.766 us; speedup vs baseline: 1.0141x; 1.0141x over previous
//
#include <hip/hip_runtime.h>
#include <math.h>

// GEBLNet via Gram-matrix reduction.
// R28 = R27 RESUBMIT (bench infra failed twice; kernel audited: no barrier
// -> no deadlock mechanism; wave-local lgkmcnt(0) fencing is sufficient for
// intra-wave LDS producer->consumer; OOB audit clean: x2<=737279/737280,
// CTt<=2027/2028, w1g<=2027/2028; static LDS 31360B < 64KiB).
// Structure: R26 per-wave code packed as 4 INDEPENDENT waves / 256-thr
// block with WAVE-LOCAL barriers (s_waitcnt lgkmcnt(0), no __syncthreads).
// EVIDENCE: wg completion rate climbed 95->127 wg/us (R17->R26) with
// shrinking per-round gains -> approaching a ~19 cy/wg single-wave-wg
// DISPATCH floor. Little's law with rate-limited arrival retro-explains
// the residency data (R21 N=8.5 @ dur 19us; R22 N=5.8 @ half wgs; R19-R26
// N~11.5). R20/R22's fewer-wg attempts failed via barrier coupling /
// doubled serial work; this is the clean test: 4 waves/block, ZERO
// inter-wave coupling (each wave owns a 7840B LDS slice).
// LEDGER: proven = conflict removal (R18), load-ILP (R19), pk-fma (R24),
// chain split (R25/R26, saturated). Falsified = VMEM count (R21), DS count
// (R23), wg-slot cap (R20), pt-amortization (R22), LDS/VGPR residency
// (R17-R19). LESSON (R6): unions, no reinterpret-cast of locals.

#define NPTS 8192
#define THRESH 0.001f

typedef float f32x2 __attribute__((ext_vector_type(2)));

// Wave-local "barrier": drain this wave's outstanding LDS ops. Sufficient
// for intra-wave producer->consumer through LDS (no inter-wave data here).
static __device__ __forceinline__ void wsync() {
    asm volatile("s_waitcnt lgkmcnt(0)" ::: "memory");
}

// --- independent halves of complex MAC: acc += cc * ee ---
static __device__ __forceinline__ void cmacA(f32x2& acc, f32x2 cc, f32x2 ee) {
    asm("v_pk_fma_f32 %0, %1, %2, %0 op_sel:[0,0,0] op_sel_hi:[0,1,1]"
        : "+v"(acc) : "v"(cc), "v"(ee));
}
static __device__ __forceinline__ void cmacB(f32x2& acc, f32x2 cc, f32x2 ee) {
    asm("v_pk_fma_f32 %0, %1, %2, %0 op_sel:[1,1,0] op_sel_hi:[1,0,1] neg_lo:[1,0,0]"
        : "+v"(acc) : "v"(cc), "v"(ee));
}
// --- independent halves of conj MAC: acc += A * conj(B) ---
static __device__ __forceinline__ void cmaccA(f32x2& acc, f32x2 A, f32x2 B) {
    asm("v_pk_fma_f32 %0, %1, %2, %0 op_sel:[0,0,0] op_sel_hi:[0,1,1] neg_hi:[1,0,0]"
        : "+v"(acc) : "v"(A), "v"(B));
}
static __device__ __forceinline__ void cmaccB(f32x2& acc, f32x2 A, f32x2 B) {
    asm("v_pk_fma_f32 %0, %1, %2, %0 op_sel:[1,1,0] op_sel_hi:[1,0,1]"
        : "+v"(acc) : "v"(A), "v"(B));
}
// --- independent halves of P5 dot ---
static __device__ __forceinline__ void cdotA(f32x2& acc, f32x2 gv, f32x2 cA) {
    asm("v_pk_fma_f32 %0, %1, %2, %0 op_sel:[0,0,0] op_sel_hi:[0,1,1]"
        : "+v"(acc) : "v"(gv), "v"(cA));
}
static __device__ __forceinline__ void cdotB(f32x2& acc, f32x2 gv, f32x2 cB) {
    asm("v_pk_fma_f32 %0, %1, %2, %0 op_sel:[1,0,0] op_sel_hi:[1,1,1]"
        : "+v"(acc) : "v"(gv), "v"(cB));
}

static __device__ __forceinline__ f32x2 c2(float2 a) {
    f32x2 r; r.x = a.x; r.y = a.y; return r;
}

__global__ void geblnet_setup(const float* __restrict__ w2,
                              float4* __restrict__ CTt) {
    int j = blockIdx.x * blockDim.x + threadIdx.x;
    if (j >= 12 * 169) return;
    int u = j / 169, it = j % 169;
    const float* W = w2 + u * 25 * 25 * 2;
#define WR(v, w) W[((v) * 25 + (w)) * 2]
#define WI(v, w) W[((v) * 25 + (w)) * 2 + 1]
    float c0, c1, c2v, c3;
    if (it < 78) {                       // S pairs, a<=b
        int q = it, a = 0;
        while (q >= 12 - a) { q -= 12 - a; ++a; }
        int b = a + q;
        float ar = WR(a, b) + (a != b ? WR(b, a) : 0.f);
        float ai = WI(a, b) + (a != b ? WI(b, a) : 0.f);
        float br = WR(12 + a, 12 + b) + (a != b ? WR(12 + b, 12 + a) : 0.f);
        float bi = WI(12 + a, 12 + b) + (a != b ? WI(12 + b, 12 + a) : 0.f);
        c0 = ar + br; c1 = bi - ai; c2v = ai + bi; c3 = ar - br;
    } else if (it < 156) {               // Hm pairs, a<=b
        int q = it - 78, a = 0;
        while (q >= 12 - a) { q -= 12 - a; ++a; }
        int b = a + q;
        if (a != b) {
            float gr = WR(a, 12 + b) + WR(12 + b, a);
            float gi = WI(a, 12 + b) + WI(12 + b, a);
            float dr = WR(b, 12 + a) + WR(12 + a, b);
            float di = WI(b, 12 + a) + WI(12 + a, b);
            c0 = gr + dr; c1 = di - gi; c2v = gi + di; c3 = gr - dr;
        } else {
            float er = WR(a, 12 + a) + WR(12 + a, a);
            float ei = WI(a, 12 + a) + WI(12 + a, a);
            c0 = er; c1 = 0.f; c2v = ei; c3 = 0.f;
        }
    } else if (it < 168) {               // trace terms
        int a = it - 156;
        float fr = WR(a, 24) + WR(24, a), fi = WI(a, 24) + WI(24, a);
        float pr = WR(12 + a, 24) + WR(24, 12 + a);
        float pi = WI(12 + a, 24) + WI(24, 12 + a);
        c0 = fr + pr; c1 = pi - fi; c2v = fi + pi; c3 = fr - pr;
    } else {                             // unit-unit
        c0 = 3.f * WR(24, 24); c1 = 0.f; c2v = 3.f * WI(24, 24); c3 = 0.f;
    }
    // Packed layout for P5: pairs (c0,c2) and (c1,c3) adjacent.
    CTt[it * 12 + u] = make_float4(c0, c2v, c1, c3);
#undef WR
#undef WI
}

// Scratch union: bs dead after phase 2b; phase-3..6 scratch reuses it.
union Scr {
    float2 bs[702];                     // B[uu][v][jk], rows exact 9 (5616 B)
    struct {
        float2 tpar[60];                // phase 5 partials
        float2 tr1[12];                 // layer-1 traces (read in phase 4)
        float  sc1[12];                 // combined gerelu+trnorm scale
    } s;
};

__global__ __launch_bounds__(256) void geblnet_main(
    const float2* __restrict__ x2,      // (8192, 10, 9) complex
    const float2* __restrict__ w1g,     // (12,13,13) complex
    const float* __restrict__ dw,       // (24,)
    const float* __restrict__ db,       // (1,)
    const float4* __restrict__ CTt,     // (169,12) packed (c0,c2,c1,c3)
    float* __restrict__ out)            // (8192,)
{
    // Per-wave LDS slices (4 waves, fully independent).
    __shared__ float2 WeGV_[4][170];    //  5440 B
    __shared__ Scr S_[4];               // 22464 B
    __shared__ float2 Hs_[4][108];      //  3456 B
    // total 31360 B -> 32768 alloc -> 5 blocks/CU by LDS (20 waves)

    const int wid = threadIdx.x >> 6;
    const int t = threadIdx.x & 63;
    const int p = blockIdx.x * 4 + wid;

    float2* WeGV = WeGV_[wid];
    Scr* Sp = &S_[wid];
    float2* Hs = Hs_[wid];

    // ---- phase 1: ONE coalesced read of x channels 4..9 (54 float2),
    //      write both We layouts (direct ch 0..5, conj-T ch 6..11) + identity.
    if (t < 54) {
        int xc = t / 9, ik = t - xc * 9;
        int i = ik / 3, j = ik - i * 3;
        float2 val = x2[(size_t)p * 90 + 36 + t];       // contiguous 432 B
        WeGV[xc * 10 + ik] = val;                        // direct
        WeGV[(6 + xc) * 10 + j * 3 + i] = make_float2(val.x, -val.y); // conj-T
    } else if (t < 63) {
        int ik = t - 54;
        WeGV[120 + ik] = make_float2((ik % 4 == 0) ? 1.f : 0.f, 0.f); // identity
    }
    wsync();

    // ---- phase 2: layer 1 on all 64 lanes, two u-half passes
    #pragma unroll 1
    for (int g = 0; g < 2; ++g) {
        const int u0 = g * 6;
        // 2a: B[uu][v][jk] = sum_w w1[u0+uu,v,w] * We[w][jk]
        //     8 chains: even/odd-w x A/B half-macros.
        {
            int uu = 0, rem = t;
            #pragma unroll 2
            for (int e = t; e < 702; e += 64) {
                int v = rem / 9, jk = rem - v * 9;
                const float2* cp = w1g + ((u0 + uu) * 13 + v) * 13; // contiguous
                f32x2 a0A = {0.f, 0.f}, a0B = {0.f, 0.f};
                f32x2 a1A = {0.f, 0.f}, a1B = {0.f, 0.f};
                #pragma unroll
                for (int w = 0; w < 12; w += 2) {
                    f32x2 c0 = c2(cp[w]),     e0 = c2(WeGV[w * 10 + jk]);
                    f32x2 c1 = c2(cp[w + 1]), e1 = c2(WeGV[(w + 1) * 10 + jk]);
                    cmacA(a0A, c0, e0);
                    cmacB(a0B, c0, e0);
                    cmacA(a1A, c1, e1);
                    cmacB(a1B, c1, e1);
                }
                {
                    f32x2 c0 = c2(cp[12]), e0 = c2(WeGV[120 + jk]);
                    cmacA(a0A, c0, e0);
                    cmacB(a0B, c0, e0);
                }
                Sp->bs[(uu * 13 + v) * 9 + jk] =
                    make_float2((a0A.x + a0B.x) + (a1A.x + a1B.x),
                                (a0A.y + a0B.y) + (a1A.y + a1B.y));
                rem += 64;
                if (rem >= 117) { rem -= 117; ++uu; }
            }
        }
        wsync();
        // 2b: H[u0+uu][i][k] = sum_{v,j} We[v][i][j] * B[uu][v][j*3+k]
        //     6 chains: 3 j-accs x A/B.
        if (t < 54) {
            int uu = t / 9, ik = t - uu * 9;
            int i = ik / 3, k = ik - i * 3;
            f32x2 h0A = {0.f, 0.f}, h0B = {0.f, 0.f};
            f32x2 h1A = {0.f, 0.f}, h1B = {0.f, 0.f};
            f32x2 h2A = {0.f, 0.f}, h2B = {0.f, 0.f};
            #pragma unroll
            for (int v = 0; v < 13; ++v) {
                const float2* a = &WeGV[v * 10 + i * 3];
                const float2* b = &Sp->bs[(uu * 13 + v) * 9 + k];
                f32x2 a0 = c2(a[0]), b0 = c2(b[0]);
                f32x2 a1 = c2(a[1]), b1 = c2(b[3]);
                f32x2 a2 = c2(a[2]), b2 = c2(b[6]);
                cmacA(h0A, a0, b0); cmacB(h0B, a0, b0);
                cmacA(h1A, a1, b1); cmacB(h1B, a1, b1);
                cmacA(h2A, a2, b2); cmacB(h2B, a2, b2);
            }
            Hs[(u0 + uu) * 9 + ik] =
                make_float2((h0A.x + h0B.x) + (h1A.x + h1B.x) + (h2A.x + h2B.x),
                            (h0A.y + h0B.y) + (h1A.y + h1B.y) + (h2A.y + h2B.y));
        }
        wsync();
    }

    // ---- phase 3: traces + gerelu + trnorm scales (shuffle reduce)
    {
        float2 tt = make_float2(0.f, 0.f);
        float gg = 0.f, tra_v = 0.f;
        if (t < 12) {
            float2 a = Hs[t * 9 + 0], b = Hs[t * 9 + 4], c = Hs[t * 9 + 8];
            tt = make_float2(a.x + b.x + c.x, a.y + b.y + c.y);
            gg = tt.x > 0.f ? tt.x : 0.f;
            tra_v = gg * sqrtf(tt.x * tt.x + tt.y * tt.y);
        }
        float m = tra_v;                 // lanes 12..15 contribute 0
        m += __shfl_xor(m, 1, 16);
        m += __shfl_xor(m, 2, 16);
        m += __shfl_xor(m, 4, 16);
        m += __shfl_xor(m, 8, 16);
        if (t < 12) {
            Sp->s.tr1[t] = tt;
            Sp->s.sc1[t] = gg / fmaxf(m * (1.f / 12.f), THRESH);
        }
    }
    wsync();

    // ---- phase 4: Gram values -> GV (overlays We row-major; dead now)
    for (int it = t; it < 169; it += 64) {
        float2 val;
        if (it < 156) {
            int q = it < 78 ? it : it - 78;
            float fs = sqrtf(625.0f - 8.0f * (float)q);   // exact at bucket edges
            int a = (int)((25.0f - fs) * 0.5f);
            int b = q - (a * (25 - a)) / 2 + a;
            const float2* Ha = &Hs[a * 9];
            const float2* Hb = &Hs[b * 9];
            float s = Sp->s.sc1[a] * Sp->s.sc1[b];
            f32x2 v0A = {0.f, 0.f}, v0B = {0.f, 0.f};
            f32x2 v1A = {0.f, 0.f}, v1B = {0.f, 0.f};
            if (it < 78) {                    // S = tr(Aa Ab)
                #pragma unroll
                for (int i = 0; i < 3; ++i)
                    #pragma unroll
                    for (int jj = 0; jj < 3; ++jj) {
                        f32x2 A = c2(Ha[i * 3 + jj]), B = c2(Hb[jj * 3 + i]);
                        if (((i * 3 + jj) & 1) == 0) {
                            cmacA(v0A, A, B); cmacB(v0B, A, B);
                        } else {
                            cmacA(v1A, A, B); cmacB(v1B, A, B);
                        }
                    }
            } else {                          // Hm = tr(Aa Ab^H)
                #pragma unroll
                for (int e = 0; e < 9; ++e) {
                    f32x2 A = c2(Ha[e]), B = c2(Hb[e]);
                    if ((e & 1) == 0) { cmaccA(v0A, A, B); cmaccB(v0B, A, B); }
                    else              { cmaccA(v1A, A, B); cmaccB(v1B, A, B); }
                }
            }
            val = make_float2(s * ((v0A.x + v0B.x) + (v1A.x + v1B.x)),
                              s * ((v0A.y + v0B.y) + (v1A.y + v1B.y)));
        } else if (it < 168) {
            int a = it - 156;
            float s = Sp->s.sc1[a]; float2 tt = Sp->s.tr1[a];
            val = make_float2(s * tt.x, s * tt.y);
        } else {
            val = make_float2(1.f, 0.f);
        }
        WeGV[it] = val;
    }
    wsync();

    // ---- phase 5: coefficient contraction, lane=(q,u), 60 active
    //      8 chains: 4x unroll x A/B, all NAMED accumulators.
    if (t < 60) {
        int q = t / 12, u = t - q * 12;
        int i0 = q * 34, i1 = (q == 4) ? 169 : i0 + 34;
        f32x2 A0 = {0.f, 0.f}, B0 = {0.f, 0.f};
        f32x2 A1 = {0.f, 0.f}, B1 = {0.f, 0.f};
        f32x2 A2 = {0.f, 0.f}, B2 = {0.f, 0.f};
        f32x2 A3 = {0.f, 0.f}, B3 = {0.f, 0.f};
        int it = i0;
        #pragma unroll 1
        for (; it + 4 <= i1; it += 4) {
            float4 c0v = CTt[(it + 0) * 12 + u];
            float4 c1v = CTt[(it + 1) * 12 + u];
            float4 c2c = CTt[(it + 2) * 12 + u];
            float4 c3v = CTt[(it + 3) * 12 + u];
            f32x2 g0 = c2(WeGV[it + 0]), g1 = c2(WeGV[it + 1]);
            f32x2 g2 = c2(WeGV[it + 2]), g3 = c2(WeGV[it + 3]);
            f32x2 cA, cB;
            cA.x = c0v.x; cA.y = c0v.y; cB.x = c0v.z; cB.y = c0v.w;
            cdotA(A0, g0, cA); cdotB(B0, g0, cB);
            cA.x = c1v.x; cA.y = c1v.y; cB.x = c1v.z; cB.y = c1v.w;
            cdotA(A1, g1, cA); cdotB(B1, g1, cB);
            cA.x = c2c.x; cA.y = c2c.y; cB.x = c2c.z; cB.y = c2c.w;
            cdotA(A2, g2, cA); cdotB(B2, g2, cB);
            cA.x = c3v.x; cA.y = c3v.y; cB.x = c3v.z; cB.y = c3v.w;
            cdotA(A3, g3, cA); cdotB(B3, g3, cB);
        }
        for (; it < i1; ++it) {
            float4 c = CTt[it * 12 + u];
            f32x2 cA, cB;
            cA.x = c.x; cA.y = c.y; cB.x = c.z; cB.y = c.w;
            f32x2 g = c2(WeGV[it]);
            cdotA(A0, g, cA); cdotB(B0, g, cB);
        }
        Sp->s.tpar[u * 5 + q] =
            make_float2(((A0.x + B0.x) + (A1.x + B1.x)) +
                        ((A2.x + B2.x) + (A3.x + B3.x)),
                        ((A0.y + B0.y) + (A1.y + B1.y)) +
                        ((A2.y + B2.y) + (A3.y + B3.y)));
    }
    wsync();

    // ---- phase 6: layer-2 gerelu + trnorm + dense head (shuffle reduce)
    {
        float2 tt = make_float2(0.f, 0.f);
        float gg = 0.f, tra_v = 0.f;
        if (t < 12) {
            #pragma unroll
            for (int q = 0; q < 5; ++q) {
                float2 A = Sp->s.tpar[t * 5 + q];
                tt.x += A.x; tt.y += A.y;
            }
            gg = tt.x > 0.f ? tt.x : 0.f;
            tra_v = gg * sqrtf(tt.x * tt.x + tt.y * tt.y);
        }
        float m = tra_v;                 // lanes 12..15 contribute 0
        m += __shfl_xor(m, 1, 16);
        m += __shfl_xor(m, 2, 16);
        m += __shfl_xor(m, 4, 16);
        m += __shfl_xor(m, 8, 16);
        float term = 0.f;
        if (t < 12) {
            float inv = 1.f / fmaxf(m * (1.f / 12.f), THRESH);
            float s = gg * inv * (1.f / 3.f);
            term = s * (tt.x * dw[2 * t] + tt.y * dw[2 * t + 1]);
        }
        term += __shfl_xor(term, 1, 16);
        term += __shfl_xor(term, 2, 16);
        term += __shfl_xor(term, 4, 16);
        term += __shfl_xor(term, 8, 16);
        if (t == 0) out[p] = term + db[0];
    }
}

extern "C" void kernel_launch(void* const* d_in, const int* in_sizes, int n_in,
                              void* d_out, int out_size, void* d_ws, size_t ws_size,
                              hipStream_t stream) {
    const float* x  = (const float*)d_in[0];
    const float* w1 = (const float*)d_in[1];
    const float* w2 = (const float*)d_in[2];
    const float* dw = (const float*)d_in[3];
    const float* db = (const float*)d_in[4];
    float* outp = (float*)d_out;
    float4* CTt = (float4*)d_ws;          // 12*169*16 B = 32448 B

    geblnet_setup<<<(12 * 169 + 255) / 256, 256, 0, stream>>>(w2, CTt);

    geblnet_main<<<NPTS / 4, 256, 0, stream>>>(
        (const float2*)x, (const float2*)w1, dw, db, CTt, outp);
}

// Round 12
// 114.381 us; speedup vs baseline: 1.0264x; 1.0121x over previous
//
#include <hip/hip_runtime.h>
#include <math.h>

// GEBLNet via Gram-matrix reduction.
// R29 = R28 shell + FORCED LOAD BATCHING. EVIDENCE: per-wave life ~62k cy
// vs ~2.6k VALU issue (96% stall) and VGPR=44 since the pk-fma rewrite ->
// the backend minimized registers for its occupancy target and serialized
// the 2a operand loads (few in flight, wait, consume, repeat). R19's only
// big win (load-ILP, VGPR 64) was exactly this buffering; R24-26 lost it.
//   (a) 2a: explicit cc[13]/ee[13] operand arrays, static-indexed, load
//       loop fully unrolled BEFORE the FMA loop -> one latency exposure
//       per job (26 operands in flight), not ~13.
//   (b) amdgpu_waves_per_eu(3): relax occupancy target to 3 waves/EU
//       (=12/CU, the measured residency anyway) -> VGPR budget ~170,
//       compiler free to keep the batches in registers.
//   (c) P5: CTt first-4 prefetch before phase 4 (R21-proven, lost in R24).
// Shell unchanged from R28: 4 independent waves / 256-thr block, wave-local
// lgkmcnt(0) fences (no s_barrier -> no deadlock path), grid 2048.
// LEDGER: proven = conflict removal (R18), load-ILP (R19), 4-wave packing
// (R28, +2us), pk-fma (R24), chain split (R25/R26, saturated). Falsified =
// VMEM count (R21), DS count (R23), wg-slot cap (R20), pt-amortization
// (R22), LDS/VGPR residency caps (R17-R19). LESSON (R6): unions only.

#define NPTS 8192
#define THRESH 0.001f

typedef float f32x2 __attribute__((ext_vector_type(2)));

// Wave-local "barrier": drain this wave's outstanding LDS ops.
static __device__ __forceinline__ void wsync() {
    asm volatile("s_waitcnt lgkmcnt(0)" ::: "memory");
}

// --- independent halves of complex MAC: acc += cc * ee ---
static __device__ __forceinline__ void cmacA(f32x2& acc, f32x2 cc, f32x2 ee) {
    asm("v_pk_fma_f32 %0, %1, %2, %0 op_sel:[0,0,0] op_sel_hi:[0,1,1]"
        : "+v"(acc) : "v"(cc), "v"(ee));
}
static __device__ __forceinline__ void cmacB(f32x2& acc, f32x2 cc, f32x2 ee) {
    asm("v_pk_fma_f32 %0, %1, %2, %0 op_sel:[1,1,0] op_sel_hi:[1,0,1] neg_lo:[1,0,0]"
        : "+v"(acc) : "v"(cc), "v"(ee));
}
// --- independent halves of conj MAC: acc += A * conj(B) ---
static __device__ __forceinline__ void cmaccA(f32x2& acc, f32x2 A, f32x2 B) {
    asm("v_pk_fma_f32 %0, %1, %2, %0 op_sel:[0,0,0] op_sel_hi:[0,1,1] neg_hi:[1,0,0]"
        : "+v"(acc) : "v"(A), "v"(B));
}
static __device__ __forceinline__ void cmaccB(f32x2& acc, f32x2 A, f32x2 B) {
    asm("v_pk_fma_f32 %0, %1, %2, %0 op_sel:[1,1,0] op_sel_hi:[1,0,1]"
        : "+v"(acc) : "v"(A), "v"(B));
}
// --- independent halves of P5 dot ---
static __device__ __forceinline__ void cdotA(f32x2& acc, f32x2 gv, f32x2 cA) {
    asm("v_pk_fma_f32 %0, %1, %2, %0 op_sel:[0,0,0] op_sel_hi:[0,1,1]"
        : "+v"(acc) : "v"(gv), "v"(cA));
}
static __device__ __forceinline__ void cdotB(f32x2& acc, f32x2 gv, f32x2 cB) {
    asm("v_pk_fma_f32 %0, %1, %2, %0 op_sel:[1,0,0] op_sel_hi:[1,1,1]"
        : "+v"(acc) : "v"(gv), "v"(cB));
}

static __device__ __forceinline__ f32x2 c2(float2 a) {
    f32x2 r; r.x = a.x; r.y = a.y; return r;
}

__global__ void geblnet_setup(const float* __restrict__ w2,
                              float4* __restrict__ CTt) {
    int j = blockIdx.x * blockDim.x + threadIdx.x;
    if (j >= 12 * 169) return;
    int u = j / 169, it = j % 169;
    const float* W = w2 + u * 25 * 25 * 2;
#define WR(v, w) W[((v) * 25 + (w)) * 2]
#define WI(v, w) W[((v) * 25 + (w)) * 2 + 1]
    float c0, c1, c2v, c3;
    if (it < 78) {                       // S pairs, a<=b
        int q = it, a = 0;
        while (q >= 12 - a) { q -= 12 - a; ++a; }
        int b = a + q;
        float ar = WR(a, b) + (a != b ? WR(b, a) : 0.f);
        float ai = WI(a, b) + (a != b ? WI(b, a) : 0.f);
        float br = WR(12 + a, 12 + b) + (a != b ? WR(12 + b, 12 + a) : 0.f);
        float bi = WI(12 + a, 12 + b) + (a != b ? WI(12 + b, 12 + a) : 0.f);
        c0 = ar + br; c1 = bi - ai; c2v = ai + bi; c3 = ar - br;
    } else if (it < 156) {               // Hm pairs, a<=b
        int q = it - 78, a = 0;
        while (q >= 12 - a) { q -= 12 - a; ++a; }
        int b = a + q;
        if (a != b) {
            float gr = WR(a, 12 + b) + WR(12 + b, a);
            float gi = WI(a, 12 + b) + WI(12 + b, a);
            float dr = WR(b, 12 + a) + WR(12 + a, b);
            float di = WI(b, 12 + a) + WI(12 + a, b);
            c0 = gr + dr; c1 = di - gi; c2v = gi + di; c3 = gr - dr;
        } else {
            float er = WR(a, 12 + a) + WR(12 + a, a);
            float ei = WI(a, 12 + a) + WI(12 + a, a);
            c0 = er; c1 = 0.f; c2v = ei; c3 = 0.f;
        }
    } else if (it < 168) {               // trace terms
        int a = it - 156;
        float fr = WR(a, 24) + WR(24, a), fi = WI(a, 24) + WI(24, a);
        float pr = WR(12 + a, 24) + WR(24, 12 + a);
        float pi = WI(12 + a, 24) + WI(24, 12 + a);
        c0 = fr + pr; c1 = pi - fi; c2v = fi + pi; c3 = fr - pr;
    } else {                             // unit-unit
        c0 = 3.f * WR(24, 24); c1 = 0.f; c2v = 3.f * WI(24, 24); c3 = 0.f;
    }
    // Packed layout for P5: pairs (c0,c2) and (c1,c3) adjacent.
    CTt[it * 12 + u] = make_float4(c0, c2v, c1, c3);
#undef WR
#undef WI
}

// Scratch union: bs dead after phase 2b; phase-3..6 scratch reuses it.
union Scr {
    float2 bs[702];                     // B[uu][v][jk], rows exact 9 (5616 B)
    struct {
        float2 tpar[60];                // phase 5 partials
        float2 tr1[12];                 // layer-1 traces (read in phase 4)
        float  sc1[12];                 // combined gerelu+trnorm scale
    } s;
};

__global__ __launch_bounds__(256)
__attribute__((amdgpu_waves_per_eu(3)))
void geblnet_main(
    const float2* __restrict__ x2,      // (8192, 10, 9) complex
    const float2* __restrict__ w1g,     // (12,13,13) complex
    const float* __restrict__ dw,       // (24,)
    const float* __restrict__ db,       // (1,)
    const float4* __restrict__ CTt,     // (169,12) packed (c0,c2,c1,c3)
    float* __restrict__ out)            // (8192,)
{
    // Per-wave LDS slices (4 waves, fully independent).
    __shared__ float2 WeGV_[4][170];    //  5440 B
    __shared__ Scr S_[4];               // 22464 B
    __shared__ float2 Hs_[4][108];      //  3456 B
    // total 31360 B

    const int wid = threadIdx.x >> 6;
    const int t = threadIdx.x & 63;
    const int p = blockIdx.x * 4 + wid;

    float2* WeGV = WeGV_[wid];
    Scr* Sp = &S_[wid];
    float2* Hs = Hs_[wid];

    // ---- phase 1: ONE coalesced read of x channels 4..9 (54 float2),
    //      write both We layouts (direct ch 0..5, conj-T ch 6..11) + identity.
    if (t < 54) {
        int xc = t / 9, ik = t - xc * 9;
        int i = ik / 3, j = ik - i * 3;
        float2 val = x2[(size_t)p * 90 + 36 + t];       // contiguous 432 B
        WeGV[xc * 10 + ik] = val;                        // direct
        WeGV[(6 + xc) * 10 + j * 3 + i] = make_float2(val.x, -val.y); // conj-T
    } else if (t < 63) {
        int ik = t - 54;
        WeGV[120 + ik] = make_float2((ik % 4 == 0) ? 1.f : 0.f, 0.f); // identity
    }
    wsync();

    // ---- phase 2: layer 1 on all 64 lanes, two u-half passes
    #pragma unroll 1
    for (int g = 0; g < 2; ++g) {
        const int u0 = g * 6;
        // 2a: B[uu][v][jk] = sum_w w1[u0+uu,v,w] * We[w][jk]
        //     FORCED BATCH: cc[13]/ee[13] loaded fully before any FMA ->
        //     one latency exposure per job. 8 chains (even/odd-w x A/B).
        {
            int uu = 0, rem = t;
            #pragma unroll 2
            for (int e = t; e < 702; e += 64) {
                int v = rem / 9, jk = rem - v * 9;
                const float2* cp = w1g + ((u0 + uu) * 13 + v) * 13; // contiguous
                f32x2 cc[13], ee[13];
                #pragma unroll
                for (int w = 0; w < 13; ++w) cc[w] = c2(cp[w]);
                #pragma unroll
                for (int w = 0; w < 13; ++w) ee[w] = c2(WeGV[w * 10 + jk]);
                f32x2 a0A = {0.f, 0.f}, a0B = {0.f, 0.f};
                f32x2 a1A = {0.f, 0.f}, a1B = {0.f, 0.f};
                #pragma unroll
                for (int w = 0; w < 12; w += 2) {
                    cmacA(a0A, cc[w], ee[w]);
                    cmacB(a0B, cc[w], ee[w]);
                    cmacA(a1A, cc[w + 1], ee[w + 1]);
                    cmacB(a1B, cc[w + 1], ee[w + 1]);
                }
                cmacA(a0A, cc[12], ee[12]);
                cmacB(a0B, cc[12], ee[12]);
                Sp->bs[(uu * 13 + v) * 9 + jk] =
                    make_float2((a0A.x + a0B.x) + (a1A.x + a1B.x),
                                (a0A.y + a0B.y) + (a1A.y + a1B.y));
                rem += 64;
                if (rem >= 117) { rem -= 117; ++uu; }
            }
        }
        wsync();
        // 2b: H[u0+uu][i][k] = sum_{v,j} We[v][i][j] * B[uu][v][j*3+k]
        //     6 chains: 3 j-accs x A/B (per-v 6-operand batches).
        if (t < 54) {
            int uu = t / 9, ik = t - uu * 9;
            int i = ik / 3, k = ik - i * 3;
            f32x2 h0A = {0.f, 0.f}, h0B = {0.f, 0.f};
            f32x2 h1A = {0.f, 0.f}, h1B = {0.f, 0.f};
            f32x2 h2A = {0.f, 0.f}, h2B = {0.f, 0.f};
            #pragma unroll
            for (int v = 0; v < 13; ++v) {
                const float2* a = &WeGV[v * 10 + i * 3];
                const float2* b = &Sp->bs[(uu * 13 + v) * 9 + k];
                f32x2 a0 = c2(a[0]), b0 = c2(b[0]);
                f32x2 a1 = c2(a[1]), b1 = c2(b[3]);
                f32x2 a2 = c2(a[2]), b2 = c2(b[6]);
                cmacA(h0A, a0, b0); cmacB(h0B, a0, b0);
                cmacA(h1A, a1, b1); cmacB(h1B, a1, b1);
                cmacA(h2A, a2, b2); cmacB(h2B, a2, b2);
            }
            Hs[(u0 + uu) * 9 + ik] =
                make_float2((h0A.x + h0B.x) + (h1A.x + h1B.x) + (h2A.x + h2B.x),
                            (h0A.y + h0B.y) + (h1A.y + h1B.y) + (h2A.y + h2B.y));
        }
        wsync();
    }

    // ---- phase 3: traces + gerelu + trnorm scales (shuffle reduce)
    {
        float2 tt = make_float2(0.f, 0.f);
        float gg = 0.f, tra_v = 0.f;
        if (t < 12) {
            float2 a = Hs[t * 9 + 0], b = Hs[t * 9 + 4], c = Hs[t * 9 + 8];
            tt = make_float2(a.x + b.x + c.x, a.y + b.y + c.y);
            gg = tt.x > 0.f ? tt.x : 0.f;
            tra_v = gg * sqrtf(tt.x * tt.x + tt.y * tt.y);
        }
        float m = tra_v;                 // lanes 12..15 contribute 0
        m += __shfl_xor(m, 1, 16);
        m += __shfl_xor(m, 2, 16);
        m += __shfl_xor(m, 4, 16);
        m += __shfl_xor(m, 8, 16);
        if (t < 12) {
            Sp->s.tr1[t] = tt;
            Sp->s.sc1[t] = gg / fmaxf(m * (1.f / 12.f), THRESH);
        }
    }
    wsync();

    // ---- phase 4 prologue: prefetch first 4 CTt rows for phase 5 (no dep)
    const int q5 = t / 12, u5 = t - q5 * 12;
    const int i0 = q5 * 34;
    const bool act5 = (t < 60);
    const int pbase = act5 ? i0 * 12 + u5 : 0;
    float4 pc0 = CTt[pbase];
    float4 pc1 = CTt[pbase + 12];
    float4 pc2 = CTt[pbase + 24];
    float4 pc3 = CTt[pbase + 36];

    // ---- phase 4: Gram values -> GV (overlays We row-major; dead now)
    for (int it = t; it < 169; it += 64) {
        float2 val;
        if (it < 156) {
            int q = it < 78 ? it : it - 78;
            float fs = sqrtf(625.0f - 8.0f * (float)q);   // exact at bucket edges
            int a = (int)((25.0f - fs) * 0.5f);
            int b = q - (a * (25 - a)) / 2 + a;
            const float2* Ha = &Hs[a * 9];
            const float2* Hb = &Hs[b * 9];
            float s = Sp->s.sc1[a] * Sp->s.sc1[b];
            f32x2 v0A = {0.f, 0.f}, v0B = {0.f, 0.f};
            f32x2 v1A = {0.f, 0.f}, v1B = {0.f, 0.f};
            if (it < 78) {                    // S = tr(Aa Ab)
                #pragma unroll
                for (int i = 0; i < 3; ++i)
                    #pragma unroll
                    for (int jj = 0; jj < 3; ++jj) {
                        f32x2 A = c2(Ha[i * 3 + jj]), B = c2(Hb[jj * 3 + i]);
                        if (((i * 3 + jj) & 1) == 0) {
                            cmacA(v0A, A, B); cmacB(v0B, A, B);
                        } else {
                            cmacA(v1A, A, B); cmacB(v1B, A, B);
                        }
                    }
            } else {                          // Hm = tr(Aa Ab^H)
                #pragma unroll
                for (int e = 0; e < 9; ++e) {
                    f32x2 A = c2(Ha[e]), B = c2(Hb[e]);
                    if ((e & 1) == 0) { cmaccA(v0A, A, B); cmaccB(v0B, A, B); }
                    else              { cmaccA(v1A, A, B); cmaccB(v1B, A, B); }
                }
            }
            val = make_float2(s * ((v0A.x + v0B.x) + (v1A.x + v1B.x)),
                              s * ((v0A.y + v0B.y) + (v1A.y + v1B.y)));
        } else if (it < 168) {
            int a = it - 156;
            float s = Sp->s.sc1[a]; float2 tt = Sp->s.tr1[a];
            val = make_float2(s * tt.x, s * tt.y);
        } else {
            val = make_float2(1.f, 0.f);
        }
        WeGV[it] = val;
    }
    wsync();

    // ---- phase 5: coefficient contraction, lane=(q,u), 60 active
    //      Prefetched first 4 rows + 8 chains (4x unroll x A/B, named accs).
    if (act5) {
        const int i1 = (q5 == 4) ? 169 : i0 + 34;
        f32x2 A0 = {0.f, 0.f}, B0 = {0.f, 0.f};
        f32x2 A1 = {0.f, 0.f}, B1 = {0.f, 0.f};
        f32x2 A2 = {0.f, 0.f}, B2 = {0.f, 0.f};
        f32x2 A3 = {0.f, 0.f}, B3 = {0.f, 0.f};
        {
            f32x2 g0 = c2(WeGV[i0 + 0]), g1 = c2(WeGV[i0 + 1]);
            f32x2 g2 = c2(WeGV[i0 + 2]), g3 = c2(WeGV[i0 + 3]);
            f32x2 cA, cB;
            cA.x = pc0.x; cA.y = pc0.y; cB.x = pc0.z; cB.y = pc0.w;
            cdotA(A0, g0, cA); cdotB(B0, g0, cB);
            cA.x = pc1.x; cA.y = pc1.y; cB.x = pc1.z; cB.y = pc1.w;
            cdotA(A1, g1, cA); cdotB(B1, g1, cB);
            cA.x = pc2.x; cA.y = pc2.y; cB.x = pc2.z; cB.y = pc2.w;
            cdotA(A2, g2, cA); cdotB(B2, g2, cB);
            cA.x = pc3.x; cA.y = pc3.y; cB.x = pc3.z; cB.y = pc3.w;
            cdotA(A3, g3, cA); cdotB(B3, g3, cB);
        }
        int it = i0 + 4;
        #pragma unroll 1
        for (; it + 4 <= i1; it += 4) {
            float4 c0v = CTt[(it + 0) * 12 + u5];
            float4 c1v = CTt[(it + 1) * 12 + u5];
            float4 c2c = CTt[(it + 2) * 12 + u5];
            float4 c3v = CTt[(it + 3) * 12 + u5];
            f32x2 g0 = c2(WeGV[it + 0]), g1 = c2(WeGV[it + 1]);
            f32x2 g2 = c2(WeGV[it + 2]), g3 = c2(WeGV[it + 3]);
            f32x2 cA, cB;
            cA.x = c0v.x; cA.y = c0v.y; cB.x = c0v.z; cB.y = c0v.w;
            cdotA(A0, g0, cA); cdotB(B0, g0, cB);
            cA.x = c1v.x; cA.y = c1v.y; cB.x = c1v.z; cB.y = c1v.w;
            cdotA(A1, g1, cA); cdotB(B1, g1, cB);
            cA.x = c2c.x; cA.y = c2c.y; cB.x = c2c.z; cB.y = c2c.w;
            cdotA(A2, g2, cA); cdotB(B2, g2, cB);
            cA.x = c3v.x; cA.y = c3v.y; cB.x = c3v.z; cB.y = c3v.w;
            cdotA(A3, g3, cA); cdotB(B3, g3, cB);
        }
        for (; it < i1; ++it) {
            float4 c = CTt[it * 12 + u5];
            f32x2 cA, cB;
            cA.x = c.x; cA.y = c.y; cB.x = c.z; cB.y = c.w;
            f32x2 g = c2(WeGV[it]);
            cdotA(A0, g, cA); cdotB(B0, g, cB);
        }
        Sp->s.tpar[u5 * 5 + q5] =
            make_float2(((A0.x + B0.x) + (A1.x + B1.x)) +
                        ((A2.x + B2.x) + (A3.x + B3.x)),
                        ((A0.y + B0.y) + (A1.y + B1.y)) +
                        ((A2.y + B2.y) + (A3.y + B3.y)));
    }
    wsync();

    // ---- phase 6: layer-2 gerelu + trnorm + dense head (shuffle reduce)
    {
        float2 tt = make_float2(0.f, 0.f);
        float gg = 0.f, tra_v = 0.f;
        if (t < 12) {
            #pragma unroll
            for (int q = 0; q < 5; ++q) {
                float2 A = Sp->s.tpar[t * 5 + q];
                tt.x += A.x; tt.y += A.y;
            }
            gg = tt.x > 0.f ? tt.x : 0.f;
            tra_v = gg * sqrtf(tt.x * tt.x + tt.y * tt.y);
        }
        float m = tra_v;                 // lanes 12..15 contribute 0
        m += __shfl_xor(m, 1, 16);
        m += __shfl_xor(m, 2, 16);
        m += __shfl_xor(m, 4, 16);
        m += __shfl_xor(m, 8, 16);
        float term = 0.f;
        if (t < 12) {
            float inv = 1.f / fmaxf(m * (1.f / 12.f), THRESH);
            float s = gg * inv * (1.f / 3.f);
            term = s * (tt.x * dw[2 * t] + tt.y * dw[2 * t + 1]);
        }
        term += __shfl_xor(term, 1, 16);
        term += __shfl_xor(term, 2, 16);
        term += __shfl_xor(term, 4, 16);
        term += __shfl_xor(term, 8, 16);
        if (t == 0) out[p] = term + db[0];
    }
}

extern "C" void kernel_launch(void* const* d_in, const int* in_sizes, int n_in,
                              void* d_out, int out_size, void* d_ws, size_t ws_size,
                              hipStream_t stream) {
    const float* x  = (const float*)d_in[0];
    const float* w1 = (const float*)d_in[1];
    const float* w2 = (const float*)d_in[2];
    const float* dw = (const float*)d_in[3];
    const float* db = (const float*)d_in[4];
    float* outp = (float*)d_out;
    float4* CTt = (float4*)d_ws;          // 12*169*16 B = 32448 B

    geblnet_setup<<<(12 * 169 + 255) / 256, 256, 0, stream>>>(w2, CTt);

    geblnet_main<<<NPTS / 4, 256, 0, stream>>>(
        (const float2*)x, (const float2*)w1, dw, db, CTt, outp);
}